// Round 7
// baseline (141.896 us; speedup 1.0000x reference)
//
#include <hip/hip_runtime.h>
#include <hip/hip_bf16.h>

#define V_N   40000
#define P_N   32
#define NTOT  (V_N * P_N)
#define VXc   0.16f
#define VYc   0.16f
#define XOFF  0.08f
#define YOFF  (-39.6f)
#define BN_EPS 1e-5f

#define SBLK  250                    // stats: 1000 waves, 10 iters x 4 voxels
#define PBLK  2048                   // pfn: 8192 waves, grid-stride 20000 pairs
#define CSTR  32
#define TICKET_OFF 6912
#define AFF_OFF    8192
#define MEANS_OFF  16384

#define FOR_S(X) X(0) X(1) X(2) X(3) X(4) X(5) X(6) X(7) X(8)
#define FOR_M(X) \
  X(0,0) X(0,1) X(0,2) X(0,3) X(0,4) X(0,5) X(0,6) X(0,7) X(0,8) \
  X(1,1) X(1,2) X(1,3) X(1,4) X(1,5) X(1,6) X(1,7) X(1,8) \
  X(2,2) X(2,3) X(2,4) X(2,5) X(2,6) X(2,7) X(2,8) \
  X(3,3) X(3,4) X(3,5) X(3,6) X(3,7) X(3,8) \
  X(4,4) X(4,5) X(4,6) X(4,7) X(4,8) \
  X(5,5) X(5,6) X(5,7) X(5,8) \
  X(6,6) X(6,7) X(6,8) \
  X(7,7) X(7,8) \
  X(8,8)

__device__ __forceinline__ float wave_sum(float x) {
#pragma unroll
    for (int m = 1; m < 64; m <<= 1) x += __shfl_xor(x, m, 64);
    return x;
}

__device__ __forceinline__ float rdlane(float x, int l) {
    return __uint_as_float(__builtin_amdgcn_readlane(__float_as_uint(x), l));
}

// ---------------------------------------------------------------------------
// Kernel 1: moments + per-voxel (mean_xyz, cx, cy) + last-block BN affine.
// 4 voxels/iter via two independent loads (ILP at 1 wave/SIMD).
// means slot: float4(mx,my,mz, cx) and cy packed into a separate array? No:
// store float4(mx,my,mz,cx) and cy in a cy[] array right after means.
// Simpler: two float4s? Keep ONE float4 (mx,my,mz,cx) + cy via coors in pfn
// would need coors again. Instead pack cy into mx's unused... just store
// TWO arrays: means4 (mx,my,mz,cx) and cyv (cy). One extra 4B load in pfn.
// ---------------------------------------------------------------------------
__global__ __launch_bounds__(256) void stats_kernel(
    const float4* __restrict__ voxels,
    const int*    __restrict__ npts_arr,
    const int*    __restrict__ coors,
    const float*  __restrict__ W,
    const float*  __restrict__ gamma,
    const float*  __restrict__ beta,
    float*        __restrict__ ws)
{
    float*  stats  = ws;
    int*    ticket = (int*)((char*)ws + TICKET_OFF);
    float*  aff    = (float*)((char*)ws + AFF_OFF);
    float4* means  = (float4*)((char*)ws + MEANS_OFF);
    float*  cyv    = (float*)((char*)ws + MEANS_OFF + V_N * 16);

    const int lane = threadIdx.x & 63;
    const int p    = lane & 31;
    const int half = lane >> 5;
    const int gw   = (blockIdx.x * 256 + threadIdx.x) >> 6;
    const int nw   = (SBLK * 256) >> 6;     // 1000 waves

#define DECL_S(i)   float S##i = 0.f;
#define DECL_M(i,j) float M##i##_##j = 0.f;
    FOR_S(DECL_S)
    FOR_M(DECL_M)

#define ACC_S(i)   S##i += f##i;
#define ACC_M(i,j) M##i##_##j = fmaf(f##i, f##j, M##i##_##j);
#define STAT_BODY(q, v)                                                       \
        {                                                                     \
            float sx = q.x, sy = q.y, sz = q.z;                               \
            _Pragma("unroll")                                                 \
            for (int m = 1; m < 32; m <<= 1) {                                \
                sx += __shfl_xor(sx, m, 64);                                  \
                sy += __shfl_xor(sy, m, 64);                                  \
                sz += __shfl_xor(sz, m, 64);                                  \
            }                                                                 \
            const int   npts = npts_arr[v];                                   \
            const float inv  = 1.f / (float)npts;                             \
            const float mx = sx * inv, my = sy * inv, mz = sz * inv;          \
            const float cx = (float)coors[2 * (v)]     * VXc + XOFF;          \
            const float cy = (float)coors[2 * (v) + 1] * VYc + YOFF;          \
            if (p == 0) { means[v] = make_float4(mx, my, mz, cx);             \
                          cyv[v] = cy; }                                      \
            const float g  = (p < npts) ? 1.f : 0.f;                          \
            const float f0 = q.x * g;                                         \
            const float f1 = q.y * g;                                         \
            const float f2 = q.z * g;                                         \
            const float f3 = q.w * g;                                         \
            const float f4 = (q.x - mx) * g;                                  \
            const float f5 = (q.y - my) * g;                                  \
            const float f6 = (q.z - mz) * g;                                  \
            const float f7 = (q.x - cx) * g;                                  \
            const float f8 = (q.y - cy) * g;                                  \
            FOR_S(ACC_S)                                                      \
            FOR_M(ACC_M)                                                      \
        }

    for (int vb = gw * 4; vb < V_N; vb += nw * 4) {   // exactly 10 iters
        const int vA = vb + half;
        const int vB = vb + 2 + half;
        float4 q1 = voxels[(size_t)vA * P_N + p];
        float4 q2 = voxels[(size_t)vB * P_N + p];
        STAT_BODY(q1, vA)
        STAT_BODY(q2, vB)
    }

#define RED_S(i)   S##i = wave_sum(S##i);
#define RED_M(i,j) M##i##_##j = wave_sum(M##i##_##j);
    FOR_S(RED_S)
    FOR_M(RED_M)

    __shared__ float red[4][54];
    const int wib = threadIdx.x >> 6;
    if (lane == 0) {
        float* r = red[wib];
        int k = 0;
#define ST_S(i)   r[k++] = S##i;
#define ST_M(i,j) r[k++] = M##i##_##j;
        FOR_S(ST_S)
        FOR_M(ST_M)
    }
    __syncthreads();
    if (threadIdx.x < 54) {
        float s = red[0][threadIdx.x] + red[1][threadIdx.x]
                + red[2][threadIdx.x] + red[3][threadIdx.x];
        atomicAdd(&stats[threadIdx.x * CSTR], s);
    }

    // ---- last block: BN affine once ----
    __threadfence();
    __shared__ int lastflag;
    if (threadIdx.x == 0)
        lastflag = (atomicAdd(ticket, 1) == SBLK - 1) ? 1 : 0;
    __syncthreads();
    if (lastflag && threadIdx.x < 64) {
        const int o = threadIdx.x;
        float st[54];
#pragma unroll
        for (int i = 0; i < 54; ++i)
            st[i] = atomicAdd(&stats[i * CSTR], 0.f);   // coherent read

        float w[9];
#pragma unroll
        for (int c = 0; c < 9; ++c) w[c] = W[o * 9 + c];

        const float invN = 1.f / (float)NTOT;
        float mean = 0.f;
#pragma unroll
        for (int c = 0; c < 9; ++c) mean = fmaf(w[c], st[c], mean);
        mean *= invN;

        float ex2 = 0.f;
        int k = 9;
#pragma unroll
        for (int i = 0; i < 9; ++i)
#pragma unroll
            for (int j = i; j < 9; ++j) {
                const float coef = (i == j) ? 1.f : 2.f;
                ex2 = fmaf(coef * w[i] * w[j], st[k], ex2);
                ++k;
            }
        ex2 *= invN;
        const float var   = ex2 - mean * mean;
        const float scale = gamma[o] * rsqrtf(var + BN_EPS);
        const float bias  = fmaf(-mean, scale, beta[o]);

        aff[0 * 64 + o] = (w[0] + w[4] + w[7]) * scale;
        aff[1 * 64 + o] = (w[1] + w[5] + w[8]) * scale;
        aff[2 * 64 + o] = (w[2] + w[6]) * scale;
        aff[3 * 64 + o] =  w[3] * scale;
        aff[4 * 64 + o] =  w[4] * scale;
        aff[5 * 64 + o] =  w[5] * scale;
        aff[6 * 64 + o] =  w[6] * scale;
        aff[7 * 64 + o] =  w[7] * scale;
        aff[8 * 64 + o] =  w[8] * scale;
        aff[9 * 64 + o] =  bias;
    }
}

// ---------------------------------------------------------------------------
// Kernel 2: lane = channel; wave = voxel pair; grid-stride; readlane
// broadcast; dual max chains; preamble = 10 coalesced loads.
// ---------------------------------------------------------------------------
__global__ __launch_bounds__(256) void pfn_kernel(
    const float4* __restrict__ voxels,
    const int*    __restrict__ npts_arr,
    const float*  __restrict__ ws,
    float*        __restrict__ out)
{
    const float*  aff   = (const float*)((const char*)ws + AFF_OFF);
    const float4* means = (const float4*)((const char*)ws + MEANS_OFF);
    const float*  cyv   = (const float*)((const char*)ws + MEANS_OFF + V_N * 16);

    const int lane = threadIdx.x & 63;
    const int wib  = threadIdx.x >> 6;

    const float a0   = aff[0 * 64 + lane];
    const float a1   = aff[1 * 64 + lane];
    const float a2   = aff[2 * 64 + lane];
    const float a3   = aff[3 * 64 + lane];
    const float u4   = aff[4 * 64 + lane];
    const float u5   = aff[5 * 64 + lane];
    const float u6   = aff[6 * 64 + lane];
    const float u7   = aff[7 * 64 + lane];
    const float u8   = aff[8 * 64 + lane];
    const float bias = aff[9 * 64 + lane];

    const int gwave = blockIdx.x * 4 + wib;

#define DOT(P_, OFS_) \
    fmaf(rdlane(q.x, (P_) + (OFS_)), a0, \
    fmaf(rdlane(q.y, (P_) + (OFS_)), a1, \
    fmaf(rdlane(q.z, (P_) + (OFS_)), a2, \
         rdlane(q.w, (P_) + (OFS_)) * a3)))

    for (int pr = gwave; pr < V_N / 2; pr += PBLK * 4) {
        const int vA = pr * 2;
        const int vB = vA + 1;

        const int vv = vA + (lane >> 5);
        const float4 q = voxels[(size_t)vv * P_N + (lane & 31)];

        const int nA = __builtin_amdgcn_readfirstlane(npts_arr[vA]);
        const int nB = __builtin_amdgcn_readfirstlane(npts_arr[vB]);

        const float4 mA = means[vA];
        const float4 mB = means[vB];
        const float cyA = cyv[vA];
        const float cyB = cyv[vB];

        const float bA = -fmaf(mA.x, u4, fmaf(mA.y, u5, fmaf(mA.z, u6,
                           fmaf(mA.w, u7, cyA * u8))));
        const float bB = -fmaf(mB.x, u4, fmaf(mB.y, u5, fmaf(mB.z, u6,
                           fmaf(mB.w, u7, cyB * u8))));

        float e0 = -3.4e38f, e1 = -3.4e38f;
        {
            int p = 0;
            for (; p + 1 < nA; p += 2) {
                const float d0 = DOT(p, 0);
                const float d1 = DOT(p + 1, 0);
                e0 = fmaxf(e0, d0);
                e1 = fmaxf(e1, d1);
            }
            if (p < nA) e0 = fmaxf(e0, DOT(p, 0));
        }
        float mfA = fmaxf(e0, e1) + bA;
        if (nA < P_N) mfA = fmaxf(mfA, 0.f);
        out[(size_t)vA * 64 + lane] = fmaxf(mfA + bias, 0.f);

        float g0 = -3.4e38f, g1 = -3.4e38f;
        {
            int p = 0;
            for (; p + 1 < nB; p += 2) {
                const float d0 = DOT(p, 32);
                const float d1 = DOT(p + 1, 32);
                g0 = fmaxf(g0, d0);
                g1 = fmaxf(g1, d1);
            }
            if (p < nB) g0 = fmaxf(g0, DOT(p, 32));
        }
        float mfB = fmaxf(g0, g1) + bB;
        if (nB < P_N) mfB = fmaxf(mfB, 0.f);
        out[(size_t)vB * 64 + lane] = fmaxf(mfB + bias, 0.f);
    }
#undef DOT
}

// ---------------------------------------------------------------------------
extern "C" void kernel_launch(void* const* d_in, const int* in_sizes, int n_in,
                              void* d_out, int out_size, void* d_ws, size_t ws_size,
                              hipStream_t stream)
{
    const float4* voxels = (const float4*)d_in[0];
    const int*    npts   = (const int*)d_in[1];
    const int*    coors  = (const int*)d_in[2];
    const float*  W      = (const float*)d_in[3];
    const float*  gamma  = (const float*)d_in[4];
    const float*  beta   = (const float*)d_in[5];
    float*        out    = (float*)d_out;
    float*        ws     = (float*)d_ws;

    hipMemsetAsync(d_ws, 0, 8192, stream);   // stats counters + ticket
    stats_kernel<<<SBLK, 256, 0, stream>>>(voxels, npts, coors, W, gamma, beta, ws);
    pfn_kernel<<<PBLK, 256, 0, stream>>>(voxels, npts, ws, out);
}

// Round 8
// 135.537 us; speedup vs baseline: 1.0469x; 1.0469x over previous
//
#include <hip/hip_runtime.h>
#include <hip/hip_bf16.h>

#define V_N   40000
#define P_N   32
#define NTOT  (V_N * P_N)
#define VXc   0.16f
#define VYc   0.16f
#define XOFF  0.08f
#define YOFF  (-39.6f)
#define BN_EPS 1e-5f

#define SBLK  512                    // stats: 2048 waves, ~10 iters x 2 voxels
#define PBLK  2048                   // pfn: 8192 waves, grid-stride 20000 pairs
#define CSTR  32                     // counter stride in floats (128 B line)
#define TICKET_OFF 6912
#define AFF_OFF    8192
#define MEANS_OFF  16384
// ws: [0,6912) padded counters | ticket | aff[10][64] | means float4[V] | cy[V]

#define FOR_S(X) X(0) X(1) X(2) X(3) X(4) X(5) X(6) X(7) X(8)
#define FOR_M(X) \
  X(0,0) X(0,1) X(0,2) X(0,3) X(0,4) X(0,5) X(0,6) X(0,7) X(0,8) \
  X(1,1) X(1,2) X(1,3) X(1,4) X(1,5) X(1,6) X(1,7) X(1,8) \
  X(2,2) X(2,3) X(2,4) X(2,5) X(2,6) X(2,7) X(2,8) \
  X(3,3) X(3,4) X(3,5) X(3,6) X(3,7) X(3,8) \
  X(4,4) X(4,5) X(4,6) X(4,7) X(4,8) \
  X(5,5) X(5,6) X(5,7) X(5,8) \
  X(6,6) X(6,7) X(6,8) \
  X(7,7) X(7,8) \
  X(8,8)

__device__ __forceinline__ float rdlane(float x, int l) {
    return __uint_as_float(__builtin_amdgcn_readlane(__float_as_uint(x), l));
}

// DPP move with zero-fill for invalid lanes (VALU pipe, no LDS traffic)
template <int CTRL>
__device__ __forceinline__ float dpp0(float x) {
    return __int_as_float(__builtin_amdgcn_update_dpp(
        0, __float_as_int(x), CTRL, 0xF, 0xF, true));
}

// sum of each 32-lane half, result broadcast to every lane of that half
__device__ __forceinline__ float half_sum32(float x, bool hi) {
    x += dpp0<0x111>(x);   // row_shr:1
    x += dpp0<0x112>(x);   // row_shr:2
    x += dpp0<0x114>(x);   // row_shr:4
    x += dpp0<0x118>(x);   // row_shr:8  -> lane15/31/47/63 hold row sums
    x += dpp0<0x142>(x);   // row_bcast15 -> lane31=sum(0..31), lane63=sum(32..63)
    const float a = rdlane(x, 31);
    const float b = rdlane(x, 63);
    return hi ? b : a;
}

// full 64-lane sum, uniform in all lanes
__device__ __forceinline__ float full_sum64(float x) {
    x += dpp0<0x111>(x);
    x += dpp0<0x112>(x);
    x += dpp0<0x114>(x);
    x += dpp0<0x118>(x);
    x += dpp0<0x142>(x);
    x += dpp0<0x143>(x);   // row_bcast31 -> lane63 = total
    return rdlane(x, 63);
}

// ---------------------------------------------------------------------------
// Kernel 1: moments + per-voxel (mean_xyz, cx) & cy + last-block BN affine.
// Wave = 2 voxels/iter (lane&31 = point, lane>>5 = voxel of pair).
// All cross-lane reduction on the VALU via DPP; LDS only for the 4-wave
// block combine. Scalars loaded before the reduce chains (latency overlap).
// ---------------------------------------------------------------------------
__global__ __launch_bounds__(256) void stats_kernel(
    const float4* __restrict__ voxels,
    const int*    __restrict__ npts_arr,
    const int*    __restrict__ coors,
    const float*  __restrict__ W,
    const float*  __restrict__ gamma,
    const float*  __restrict__ beta,
    float*        __restrict__ ws)
{
    float*  stats  = ws;
    int*    ticket = (int*)((char*)ws + TICKET_OFF);
    float*  aff    = (float*)((char*)ws + AFF_OFF);
    float4* means  = (float4*)((char*)ws + MEANS_OFF);
    float*  cyv    = (float*)((char*)ws + MEANS_OFF + V_N * 16);

    const int  lane = threadIdx.x & 63;
    const int  p    = lane & 31;
    const bool hi   = lane >= 32;
    const int  gw   = (blockIdx.x * 256 + threadIdx.x) >> 6;
    const int  nw   = (SBLK * 256) >> 6;     // 2048 waves

#define DECL_S(i)   float S##i = 0.f;
#define DECL_M(i,j) float M##i##_##j = 0.f;
    FOR_S(DECL_S)
    FOR_M(DECL_M)

    for (int vb = gw * 2; vb < V_N; vb += nw * 2) {
        const int v = vb + (hi ? 1 : 0);
        // issue all global loads before the reduce chains
        const float4 q    = voxels[(size_t)v * P_N + p];
        const int    npts = npts_arr[v];
        const int2   cr   = ((const int2*)coors)[v];

        const float inv = 1.f / (float)npts;
        const float mx  = half_sum32(q.x, hi) * inv;
        const float my  = half_sum32(q.y, hi) * inv;
        const float mz  = half_sum32(q.z, hi) * inv;
        const float cx  = (float)cr.x * VXc + XOFF;
        const float cy  = (float)cr.y * VYc + YOFF;

        if (p == 0) { means[v] = make_float4(mx, my, mz, cx); cyv[v] = cy; }

        const float g  = (p < npts) ? 1.f : 0.f;
        const float f0 = q.x * g;
        const float f1 = q.y * g;
        const float f2 = q.z * g;
        const float f3 = q.w * g;
        const float f4 = (q.x - mx) * g;
        const float f5 = (q.y - my) * g;
        const float f6 = (q.z - mz) * g;
        const float f7 = (q.x - cx) * g;
        const float f8 = (q.y - cy) * g;

#define ACC_S(i)   S##i += f##i;
#define ACC_M(i,j) M##i##_##j = fmaf(f##i, f##j, M##i##_##j);
        FOR_S(ACC_S)
        FOR_M(ACC_M)
    }

    // wave totals via DPP (uniform in all lanes afterwards)
#define RED_S(i)   S##i = full_sum64(S##i);
#define RED_M(i,j) M##i##_##j = full_sum64(M##i##_##j);
    FOR_S(RED_S)
    FOR_M(RED_M)

    __shared__ float red[4][54];
    const int wib = threadIdx.x >> 6;
    if (lane == 0) {
        float* r = red[wib];
        int k = 0;
#define ST_S(i)   r[k++] = S##i;
#define ST_M(i,j) r[k++] = M##i##_##j;
        FOR_S(ST_S)
        FOR_M(ST_M)
    }
    __syncthreads();
    if (threadIdx.x < 54) {
        float s = red[0][threadIdx.x] + red[1][threadIdx.x]
                + red[2][threadIdx.x] + red[3][threadIdx.x];
        atomicAdd(&stats[threadIdx.x * CSTR], s);   // distinct line per counter
    }

    // ---- last block: BN affine once ----
    __threadfence();
    __shared__ int lastflag;
    if (threadIdx.x == 0)
        lastflag = (atomicAdd(ticket, 1) == SBLK - 1) ? 1 : 0;
    __syncthreads();
    if (lastflag) {
        __shared__ float stc[54];
        // 54 PARALLEL atomic reads (one thread per counter, distinct lines),
        // NOT 64x54 same-address RMWs (that was R7's 30us tail).
        if (threadIdx.x < 54)
            stc[threadIdx.x] = atomicAdd(&stats[threadIdx.x * CSTR], 0.f);
        __syncthreads();
        if (threadIdx.x < 64) {
            const int o = threadIdx.x;
            float w[9];
#pragma unroll
            for (int c = 0; c < 9; ++c) w[c] = W[o * 9 + c];

            const float invN = 1.f / (float)NTOT;
            float mean = 0.f;
#pragma unroll
            for (int c = 0; c < 9; ++c) mean = fmaf(w[c], stc[c], mean);
            mean *= invN;

            float ex2 = 0.f;
            int k = 9;
#pragma unroll
            for (int i = 0; i < 9; ++i)
#pragma unroll
                for (int j = i; j < 9; ++j) {
                    const float coef = (i == j) ? 1.f : 2.f;
                    ex2 = fmaf(coef * w[i] * w[j], stc[k], ex2);
                    ++k;
                }
            ex2 *= invN;
            const float var   = ex2 - mean * mean;
            const float scale = gamma[o] * rsqrtf(var + BN_EPS);
            const float bias  = fmaf(-mean, scale, beta[o]);

            aff[0 * 64 + o] = (w[0] + w[4] + w[7]) * scale;
            aff[1 * 64 + o] = (w[1] + w[5] + w[8]) * scale;
            aff[2 * 64 + o] = (w[2] + w[6]) * scale;
            aff[3 * 64 + o] =  w[3] * scale;
            aff[4 * 64 + o] =  w[4] * scale;
            aff[5 * 64 + o] =  w[5] * scale;
            aff[6 * 64 + o] =  w[6] * scale;
            aff[7 * 64 + o] =  w[7] * scale;
            aff[8 * 64 + o] =  w[8] * scale;
            aff[9 * 64 + o] =  bias;
        }
    }
}

// ---------------------------------------------------------------------------
// Kernel 2 (unchanged from R7): lane = channel; wave = voxel pair;
// grid-stride; readlane broadcast; dual max chains; 10-load preamble.
// ---------------------------------------------------------------------------
__global__ __launch_bounds__(256) void pfn_kernel(
    const float4* __restrict__ voxels,
    const int*    __restrict__ npts_arr,
    const float*  __restrict__ ws,
    float*        __restrict__ out)
{
    const float*  aff   = (const float*)((const char*)ws + AFF_OFF);
    const float4* means = (const float4*)((const char*)ws + MEANS_OFF);
    const float*  cyv   = (const float*)((const char*)ws + MEANS_OFF + V_N * 16);

    const int lane = threadIdx.x & 63;
    const int wib  = threadIdx.x >> 6;

    const float a0   = aff[0 * 64 + lane];
    const float a1   = aff[1 * 64 + lane];
    const float a2   = aff[2 * 64 + lane];
    const float a3   = aff[3 * 64 + lane];
    const float u4   = aff[4 * 64 + lane];
    const float u5   = aff[5 * 64 + lane];
    const float u6   = aff[6 * 64 + lane];
    const float u7   = aff[7 * 64 + lane];
    const float u8   = aff[8 * 64 + lane];
    const float bias = aff[9 * 64 + lane];

    const int gwave = blockIdx.x * 4 + wib;

#define DOT(P_, OFS_) \
    fmaf(rdlane(q.x, (P_) + (OFS_)), a0, \
    fmaf(rdlane(q.y, (P_) + (OFS_)), a1, \
    fmaf(rdlane(q.z, (P_) + (OFS_)), a2, \
         rdlane(q.w, (P_) + (OFS_)) * a3)))

    for (int pr = gwave; pr < V_N / 2; pr += PBLK * 4) {
        const int vA = pr * 2;
        const int vB = vA + 1;

        const int vv = vA + (lane >> 5);
        const float4 q = voxels[(size_t)vv * P_N + (lane & 31)];

        const int nA = __builtin_amdgcn_readfirstlane(npts_arr[vA]);
        const int nB = __builtin_amdgcn_readfirstlane(npts_arr[vB]);

        const float4 mA = means[vA];
        const float4 mB = means[vB];
        const float cyA = cyv[vA];
        const float cyB = cyv[vB];

        const float bA = -fmaf(mA.x, u4, fmaf(mA.y, u5, fmaf(mA.z, u6,
                           fmaf(mA.w, u7, cyA * u8))));
        const float bB = -fmaf(mB.x, u4, fmaf(mB.y, u5, fmaf(mB.z, u6,
                           fmaf(mB.w, u7, cyB * u8))));

        float e0 = -3.4e38f, e1 = -3.4e38f;
        {
            int p = 0;
            for (; p + 1 < nA; p += 2) {
                const float d0 = DOT(p, 0);
                const float d1 = DOT(p + 1, 0);
                e0 = fmaxf(e0, d0);
                e1 = fmaxf(e1, d1);
            }
            if (p < nA) e0 = fmaxf(e0, DOT(p, 0));
        }
        float mfA = fmaxf(e0, e1) + bA;
        if (nA < P_N) mfA = fmaxf(mfA, 0.f);
        out[(size_t)vA * 64 + lane] = fmaxf(mfA + bias, 0.f);

        float g0 = -3.4e38f, g1 = -3.4e38f;
        {
            int p = 0;
            for (; p + 1 < nB; p += 2) {
                const float d0 = DOT(p, 32);
                const float d1 = DOT(p + 1, 32);
                g0 = fmaxf(g0, d0);
                g1 = fmaxf(g1, d1);
            }
            if (p < nB) g0 = fmaxf(g0, DOT(p, 32));
        }
        float mfB = fmaxf(g0, g1) + bB;
        if (nB < P_N) mfB = fmaxf(mfB, 0.f);
        out[(size_t)vB * 64 + lane] = fmaxf(mfB + bias, 0.f);
    }
#undef DOT
}

// ---------------------------------------------------------------------------
extern "C" void kernel_launch(void* const* d_in, const int* in_sizes, int n_in,
                              void* d_out, int out_size, void* d_ws, size_t ws_size,
                              hipStream_t stream)
{
    const float4* voxels = (const float4*)d_in[0];
    const int*    npts   = (const int*)d_in[1];
    const int*    coors  = (const int*)d_in[2];
    const float*  W      = (const float*)d_in[3];
    const float*  gamma  = (const float*)d_in[4];
    const float*  beta   = (const float*)d_in[5];
    float*        out    = (float*)d_out;
    float*        ws     = (float*)d_ws;

    hipMemsetAsync(d_ws, 0, 8192, stream);   // counters + ticket
    stats_kernel<<<SBLK, 256, 0, stream>>>(voxels, npts, coors, W, gamma, beta, ws);
    pfn_kernel<<<PBLK, 256, 0, stream>>>(voxels, npts, ws, out);
}

// Round 9
// 127.725 us; speedup vs baseline: 1.1110x; 1.0612x over previous
//
#include <hip/hip_runtime.h>
#include <hip/hip_bf16.h>

#define V_N   40000
#define P_N   32
#define NTOT  (V_N * P_N)
#define VXc   0.16f
#define VYc   0.16f
#define XOFF  0.08f
#define YOFF  (-39.6f)
#define BN_EPS 1e-5f

#define SBLK  250                    // stats: 1000 waves x 10 iters x 4 voxels
#define PBLK  2048                   // pfn: 8192 waves, grid-stride 20000 pairs
// ws layout (plain stores only, no zeroing needed):
#define PART_OFF  0                  // partials[SBLK][64] floats = 64000 B
#define AFF_OFF   65536              // aff[10][64]
#define MEANS_OFF 73728              // float4[V_N] = 640000 B
#define CY_OFF    (MEANS_OFF + 640000)

#define FOR_S(X) X(0) X(1) X(2) X(3) X(4) X(5) X(6) X(7) X(8)
#define FOR_M(X) \
  X(0,0) X(0,1) X(0,2) X(0,3) X(0,4) X(0,5) X(0,6) X(0,7) X(0,8) \
  X(1,1) X(1,2) X(1,3) X(1,4) X(1,5) X(1,6) X(1,7) X(1,8) \
  X(2,2) X(2,3) X(2,4) X(2,5) X(2,6) X(2,7) X(2,8) \
  X(3,3) X(3,4) X(3,5) X(3,6) X(3,7) X(3,8) \
  X(4,4) X(4,5) X(4,6) X(4,7) X(4,8) \
  X(5,5) X(5,6) X(5,7) X(5,8) \
  X(6,6) X(6,7) X(6,8) \
  X(7,7) X(7,8) \
  X(8,8)

__device__ __forceinline__ float wave_sum(float x) {
#pragma unroll
    for (int m = 1; m < 64; m <<= 1) x += __shfl_xor(x, m, 64);
    return x;
}

__device__ __forceinline__ float rdlane(float x, int l) {
    return __uint_as_float(__builtin_amdgcn_readlane(__float_as_uint(x), l));
}

#define DECL_S(i)   float S##i = 0.f;
#define DECL_M(i,j) float M##i##_##j = 0.f;
#define ACC_S(i)    S##i += f##i;
#define ACC_M(i,j)  M##i##_##j = fmaf(f##i, f##j, M##i##_##j);
#define RED_S(i)    S##i = wave_sum(S##i);
#define RED_M(i,j)  M##i##_##j = wave_sum(M##i##_##j);
#define ST_S(i)     r[k++] = S##i;
#define ST_M(i,j)   r[k++] = M##i##_##j;

// per-voxel-pair stat accumulation; masks 1..16 stay within each 32-lane half
#define STAT_BODY(q, v)                                                       \
        {                                                                     \
            float sx = q.x, sy = q.y, sz = q.z;                               \
            _Pragma("unroll")                                                 \
            for (int m = 1; m < 32; m <<= 1) {                                \
                sx += __shfl_xor(sx, m, 64);                                  \
                sy += __shfl_xor(sy, m, 64);                                  \
                sz += __shfl_xor(sz, m, 64);                                  \
            }                                                                 \
            const int   npts = npts_arr[v];                                   \
            const float inv  = 1.f / (float)npts;                             \
            const float mx = sx * inv, my = sy * inv, mz = sz * inv;          \
            const float cx = (float)coors[2 * (v)]     * VXc + XOFF;          \
            const float cy = (float)coors[2 * (v) + 1] * VYc + YOFF;          \
            if (p == 0) { means[v] = make_float4(mx, my, mz, cx);             \
                          cyv[v] = cy; }                                      \
            const float g  = (p < npts) ? 1.f : 0.f;                          \
            const float f0 = q.x * g;                                         \
            const float f1 = q.y * g;                                         \
            const float f2 = q.z * g;                                         \
            const float f3 = q.w * g;                                         \
            const float f4 = (q.x - mx) * g;                                  \
            const float f5 = (q.y - my) * g;                                  \
            const float f6 = (q.z - mz) * g;                                  \
            const float f7 = (q.x - cx) * g;                                  \
            const float f8 = (q.y - cy) * g;                                  \
            FOR_S(ACC_S)                                                      \
            FOR_M(ACC_M)                                                      \
        }

// ---------------------------------------------------------------------------
// Kernel 1: moment partials (per-block, plain stores -- NO global atomics,
// NO ticket, NO threadfence) + per-voxel (mean_xyz, cx) & cy.
// Wave = 4 voxels/iter via 2 independent 1-KiB loads.
// ---------------------------------------------------------------------------
__global__ __launch_bounds__(256) void stats_kernel(
    const float4* __restrict__ voxels,
    const int*    __restrict__ npts_arr,
    const int*    __restrict__ coors,
    float*        __restrict__ ws)
{
    float*  partials = ws;                                  // [SBLK][64]
    float4* means    = (float4*)((char*)ws + MEANS_OFF);
    float*  cyv      = (float*)((char*)ws + CY_OFF);

    const int lane = threadIdx.x & 63;
    const int p    = lane & 31;
    const int half = lane >> 5;
    const int gw   = (blockIdx.x * 256 + threadIdx.x) >> 6;
    const int nw   = (SBLK * 256) >> 6;     // 1000 waves

    FOR_S(DECL_S)
    FOR_M(DECL_M)

    for (int vb = gw * 4; vb < V_N; vb += nw * 4) {   // exactly 10 iters
        const int vA = vb + half;
        const int vB = vb + 2 + half;
        float4 q1 = voxels[(size_t)vA * P_N + p];     // both loads in flight
        float4 q2 = voxels[(size_t)vB * P_N + p];
        STAT_BODY(q1, vA)
        STAT_BODY(q2, vB)
    }

    FOR_S(RED_S)
    FOR_M(RED_M)

    __shared__ float red[4][54];
    const int wib = threadIdx.x >> 6;
    if (lane == 0) {
        float* r = red[wib];
        int k = 0;
        FOR_S(ST_S)
        FOR_M(ST_M)
    }
    __syncthreads();
    if (threadIdx.x < 64) {
        float s = 0.f;
        if (threadIdx.x < 54)
            s = red[0][threadIdx.x] + red[1][threadIdx.x]
              + red[2][threadIdx.x] + red[3][threadIdx.x];
        partials[blockIdx.x * 64 + threadIdx.x] = s;   // plain coalesced store
    }
}

// ---------------------------------------------------------------------------
// Kernel 1b: sum the 250 partial rows, compute BN affine table (one block).
// ---------------------------------------------------------------------------
__global__ __launch_bounds__(256) void affine_kernel(
    const float* __restrict__ W,
    const float* __restrict__ gamma,
    const float* __restrict__ beta,
    float*       __restrict__ ws)
{
    const float* partials = ws;
    float*       aff      = (float*)((char*)ws + AFF_OFF);

    __shared__ float red2[4][64];
    __shared__ float stc[64];

    const int c   = threadIdx.x & 63;
    const int seg = threadIdx.x >> 6;

    float s = 0.f;
    for (int r = seg; r < SBLK; r += 4)        // coalesced 256B rows
        s += partials[r * 64 + c];
    red2[seg][c] = s;
    __syncthreads();
    if (threadIdx.x < 64)
        stc[threadIdx.x] = red2[0][threadIdx.x] + red2[1][threadIdx.x]
                         + red2[2][threadIdx.x] + red2[3][threadIdx.x];
    __syncthreads();

    if (threadIdx.x < 64) {
        const int o = threadIdx.x;
        float w[9];
#pragma unroll
        for (int cc = 0; cc < 9; ++cc) w[cc] = W[o * 9 + cc];

        const float invN = 1.f / (float)NTOT;
        float mean = 0.f;
#pragma unroll
        for (int cc = 0; cc < 9; ++cc) mean = fmaf(w[cc], stc[cc], mean);
        mean *= invN;

        float ex2 = 0.f;
        int k = 9;
#pragma unroll
        for (int i = 0; i < 9; ++i)
#pragma unroll
            for (int j = i; j < 9; ++j) {
                const float coef = (i == j) ? 1.f : 2.f;
                ex2 = fmaf(coef * w[i] * w[j], stc[k], ex2);
                ++k;
            }
        ex2 *= invN;
        const float var   = ex2 - mean * mean;
        const float scale = gamma[o] * rsqrtf(var + BN_EPS);
        const float bias  = fmaf(-mean, scale, beta[o]);

        aff[0 * 64 + o] = (w[0] + w[4] + w[7]) * scale;
        aff[1 * 64 + o] = (w[1] + w[5] + w[8]) * scale;
        aff[2 * 64 + o] = (w[2] + w[6]) * scale;
        aff[3 * 64 + o] =  w[3] * scale;
        aff[4 * 64 + o] =  w[4] * scale;
        aff[5 * 64 + o] =  w[5] * scale;
        aff[6 * 64 + o] =  w[6] * scale;
        aff[7 * 64 + o] =  w[7] * scale;
        aff[8 * 64 + o] =  w[8] * scale;
        aff[9 * 64 + o] =  bias;
    }
}

// ---------------------------------------------------------------------------
// Kernel 2 (frozen from R8 apart from ws offsets): lane = channel; wave =
// voxel pair; grid-stride; readlane broadcast; dual max chains.
// ---------------------------------------------------------------------------
__global__ __launch_bounds__(256) void pfn_kernel(
    const float4* __restrict__ voxels,
    const int*    __restrict__ npts_arr,
    const float*  __restrict__ ws,
    float*        __restrict__ out)
{
    const float*  aff   = (const float*)((const char*)ws + AFF_OFF);
    const float4* means = (const float4*)((const char*)ws + MEANS_OFF);
    const float*  cyv   = (const float*)((const char*)ws + CY_OFF);

    const int lane = threadIdx.x & 63;
    const int wib  = threadIdx.x >> 6;

    const float a0   = aff[0 * 64 + lane];
    const float a1   = aff[1 * 64 + lane];
    const float a2   = aff[2 * 64 + lane];
    const float a3   = aff[3 * 64 + lane];
    const float u4   = aff[4 * 64 + lane];
    const float u5   = aff[5 * 64 + lane];
    const float u6   = aff[6 * 64 + lane];
    const float u7   = aff[7 * 64 + lane];
    const float u8   = aff[8 * 64 + lane];
    const float bias = aff[9 * 64 + lane];

    const int gwave = blockIdx.x * 4 + wib;

#define DOT(P_, OFS_) \
    fmaf(rdlane(q.x, (P_) + (OFS_)), a0, \
    fmaf(rdlane(q.y, (P_) + (OFS_)), a1, \
    fmaf(rdlane(q.z, (P_) + (OFS_)), a2, \
         rdlane(q.w, (P_) + (OFS_)) * a3)))

    for (int pr = gwave; pr < V_N / 2; pr += PBLK * 4) {
        const int vA = pr * 2;
        const int vB = vA + 1;

        const int vv = vA + (lane >> 5);
        const float4 q = voxels[(size_t)vv * P_N + (lane & 31)];

        const int nA = __builtin_amdgcn_readfirstlane(npts_arr[vA]);
        const int nB = __builtin_amdgcn_readfirstlane(npts_arr[vB]);

        const float4 mA = means[vA];
        const float4 mB = means[vB];
        const float cyA = cyv[vA];
        const float cyB = cyv[vB];

        const float bA = -fmaf(mA.x, u4, fmaf(mA.y, u5, fmaf(mA.z, u6,
                           fmaf(mA.w, u7, cyA * u8))));
        const float bB = -fmaf(mB.x, u4, fmaf(mB.y, u5, fmaf(mB.z, u6,
                           fmaf(mB.w, u7, cyB * u8))));

        float e0 = -3.4e38f, e1 = -3.4e38f;
        {
            int p = 0;
            for (; p + 1 < nA; p += 2) {
                const float d0 = DOT(p, 0);
                const float d1 = DOT(p + 1, 0);
                e0 = fmaxf(e0, d0);
                e1 = fmaxf(e1, d1);
            }
            if (p < nA) e0 = fmaxf(e0, DOT(p, 0));
        }
        float mfA = fmaxf(e0, e1) + bA;
        if (nA < P_N) mfA = fmaxf(mfA, 0.f);
        out[(size_t)vA * 64 + lane] = fmaxf(mfA + bias, 0.f);

        float g0 = -3.4e38f, g1 = -3.4e38f;
        {
            int p = 0;
            for (; p + 1 < nB; p += 2) {
                const float d0 = DOT(p, 32);
                const float d1 = DOT(p + 1, 32);
                g0 = fmaxf(g0, d0);
                g1 = fmaxf(g1, d1);
            }
            if (p < nB) g0 = fmaxf(g0, DOT(p, 32));
        }
        float mfB = fmaxf(g0, g1) + bB;
        if (nB < P_N) mfB = fmaxf(mfB, 0.f);
        out[(size_t)vB * 64 + lane] = fmaxf(mfB + bias, 0.f);
    }
#undef DOT
}

// ---------------------------------------------------------------------------
extern "C" void kernel_launch(void* const* d_in, const int* in_sizes, int n_in,
                              void* d_out, int out_size, void* d_ws, size_t ws_size,
                              hipStream_t stream)
{
    const float4* voxels = (const float4*)d_in[0];
    const int*    npts   = (const int*)d_in[1];
    const int*    coors  = (const int*)d_in[2];
    const float*  W      = (const float*)d_in[3];
    const float*  gamma  = (const float*)d_in[4];
    const float*  beta   = (const float*)d_in[5];
    float*        out    = (float*)d_out;
    float*        ws     = (float*)d_ws;

    stats_kernel <<<SBLK, 256, 0, stream>>>(voxels, npts, coors, ws);
    affine_kernel<<<1,    256, 0, stream>>>(W, gamma, beta, ws);
    pfn_kernel   <<<PBLK, 256, 0, stream>>>(voxels, npts, ws, out);
}

// Round 11
// 115.688 us; speedup vs baseline: 1.2265x; 1.1041x over previous
//
#include <hip/hip_runtime.h>
#include <hip/hip_bf16.h>

#define V_N   40000
#define P_N   32
#define NTOT  (V_N * P_N)
#define VXc   0.16f
#define VYc   0.16f
#define XOFF  0.08f
#define YOFF  (-39.6f)
#define BN_EPS 1e-5f

#define SBLK  250                    // stats: 1000 waves x 10 iters x 4 voxels
#define PBLK  2500                   // pfn: 10000 waves x exactly 2 pairs
#define NSHARD 8                     // atomic shards per counter
// counter (i, shard s) lives at float index (i*NSHARD+s)*32  (own 128B line)
#define CNT_BYTES  (54 * NSHARD * 32 * 4)     // 55296
#define MEANS_OFF  57344                      // float4[V_N]
#define CY_OFF     (MEANS_OFF + V_N * 16)     // float[V_N]

#define FOR_S(X) X(0) X(1) X(2) X(3) X(4) X(5) X(6) X(7) X(8)
#define FOR_M(X) \
  X(0,0) X(0,1) X(0,2) X(0,3) X(0,4) X(0,5) X(0,6) X(0,7) X(0,8) \
  X(1,1) X(1,2) X(1,3) X(1,4) X(1,5) X(1,6) X(1,7) X(1,8) \
  X(2,2) X(2,3) X(2,4) X(2,5) X(2,6) X(2,7) X(2,8) \
  X(3,3) X(3,4) X(3,5) X(3,6) X(3,7) X(3,8) \
  X(4,4) X(4,5) X(4,6) X(4,7) X(4,8) \
  X(5,5) X(5,6) X(5,7) X(5,8) \
  X(6,6) X(6,7) X(6,8) \
  X(7,7) X(7,8) \
  X(8,8)

__device__ __forceinline__ float wave_sum(float x) {
#pragma unroll
    for (int m = 1; m < 64; m <<= 1) x += __shfl_xor(x, m, 64);
    return x;
}

__device__ __forceinline__ float rdlane(float x, int l) {
    return __uint_as_float(__builtin_amdgcn_readlane(__float_as_uint(x), l));
}

#define DECL_S(i)   float S##i = 0.f;
#define DECL_M(i,j) float M##i##_##j = 0.f;
#define ACC_S(i)    S##i += f##i;
#define ACC_M(i,j)  M##i##_##j = fmaf(f##i, f##j, M##i##_##j);
#define RED_S(i)    S##i = wave_sum(S##i);
#define RED_M(i,j)  M##i##_##j = wave_sum(M##i##_##j);
#define ST_S(i)     r[k++] = S##i;
#define ST_M(i,j)   r[k++] = M##i##_##j;

// per-voxel-pair stat accumulation; masks 1..16 stay within each 32-lane half
#define STAT_BODY(q, v)                                                       \
        {                                                                     \
            float sx = q.x, sy = q.y, sz = q.z;                               \
            _Pragma("unroll")                                                 \
            for (int m = 1; m < 32; m <<= 1) {                                \
                sx += __shfl_xor(sx, m, 64);                                  \
                sy += __shfl_xor(sy, m, 64);                                  \
                sz += __shfl_xor(sz, m, 64);                                  \
            }                                                                 \
            const int   npts = npts_arr[v];                                   \
            const float inv  = 1.f / (float)npts;                             \
            const float mx = sx * inv, my = sy * inv, mz = sz * inv;          \
            const float cx = (float)coors[2 * (v)]     * VXc + XOFF;          \
            const float cy = (float)coors[2 * (v) + 1] * VYc + YOFF;          \
            if (p == 0) { means[v] = make_float4(mx, my, mz, cx);             \
                          cyv[v] = cy; }                                      \
            const float g  = (p < npts) ? 1.f : 0.f;                          \
            const float f0 = q.x * g;                                         \
            const float f1 = q.y * g;                                         \
            const float f2 = q.z * g;                                         \
            const float f3 = q.w * g;                                         \
            const float f4 = (q.x - mx) * g;                                  \
            const float f5 = (q.y - my) * g;                                  \
            const float f6 = (q.z - mz) * g;                                  \
            const float f7 = (q.x - cx) * g;                                  \
            const float f8 = (q.y - cy) * g;                                  \
            FOR_S(ACC_S)                                                      \
            FOR_M(ACC_M)                                                      \
        }

// ---------------------------------------------------------------------------
// Kernel 1: moments -> 8-way sharded padded atomic counters (~31 serialized
// RMWs per line) + per-voxel (mean_xyz, cx) & cy. 4 voxels/iter, 2 loads in
// flight. No ticket, no fence, no separate affine dispatch.
// ---------------------------------------------------------------------------
__global__ __launch_bounds__(256) void stats_kernel(
    const float4* __restrict__ voxels,
    const int*    __restrict__ npts_arr,
    const int*    __restrict__ coors,
    float*        __restrict__ ws)
{
    float*  cnt   = ws;
    float4* means = (float4*)((char*)ws + MEANS_OFF);
    float*  cyv   = (float*)((char*)ws + CY_OFF);

    const int lane = threadIdx.x & 63;
    const int p    = lane & 31;
    const int half = lane >> 5;
    const int gw   = (blockIdx.x * 256 + threadIdx.x) >> 6;
    const int nw   = (SBLK * 256) >> 6;     // 1000 waves

    FOR_S(DECL_S)
    FOR_M(DECL_M)

    for (int vb = gw * 4; vb < V_N; vb += nw * 4) {   // exactly 10 iters
        const int vA = vb + half;
        const int vB = vb + 2 + half;
        float4 q1 = voxels[(size_t)vA * P_N + p];     // both loads in flight
        float4 q2 = voxels[(size_t)vB * P_N + p];
        STAT_BODY(q1, vA)
        STAT_BODY(q2, vB)
    }

    FOR_S(RED_S)
    FOR_M(RED_M)

    __shared__ float red[4][54];
    const int wib = threadIdx.x >> 6;
    if (lane == 0) {
        float* r = red[wib];
        int k = 0;
        FOR_S(ST_S)
        FOR_M(ST_M)
    }
    __syncthreads();
    if (threadIdx.x < 54) {
        float s = red[0][threadIdx.x] + red[1][threadIdx.x]
                + red[2][threadIdx.x] + red[3][threadIdx.x];
        atomicAdd(&cnt[(threadIdx.x * NSHARD + (blockIdx.x & (NSHARD - 1))) * 32], s);
    }
}

// ---------------------------------------------------------------------------
// Kernel 2: per-block head computes the BN affine table from the sharded
// counters (plain loads -- kernel boundary gives coherence; 55KB L3-hot),
// LDS-broadcasts it, then the balanced pfn loop: 4 waves x exactly 2 pairs.
// ---------------------------------------------------------------------------
__global__ __launch_bounds__(256) void pfn_kernel(
    const float4* __restrict__ voxels,
    const int*    __restrict__ npts_arr,
    const float*  __restrict__ W,        // (64, 9) row-major
    const float*  __restrict__ gamma,
    const float*  __restrict__ beta,
    const float*  __restrict__ ws,
    float*        __restrict__ out)      // (V, 64)
{
    const float*  cnt   = ws;
    const float4* means = (const float4*)((const char*)ws + MEANS_OFF);
    const float*  cyv   = (const float*)((const char*)ws + CY_OFF);

    __shared__ float stc[54];
    __shared__ float affs[10][64];

    const int lane = threadIdx.x & 63;
    const int wib  = threadIdx.x >> 6;

    // --- block head: shard-sum + affine (fully parallel across blocks) ---
    if (threadIdx.x < 54) {
        float s = 0.f;
#pragma unroll
        for (int sh = 0; sh < NSHARD; ++sh)
            s += cnt[(threadIdx.x * NSHARD + sh) * 32];
        stc[threadIdx.x] = s;
    }
    __syncthreads();
    if (threadIdx.x < 64) {
        const int o = threadIdx.x;
        float w[9];
#pragma unroll
        for (int c = 0; c < 9; ++c) w[c] = W[o * 9 + c];

        const float invN = 1.f / (float)NTOT;
        float mean = 0.f;
#pragma unroll
        for (int c = 0; c < 9; ++c) mean = fmaf(w[c], stc[c], mean);
        mean *= invN;

        float ex2 = 0.f;
        int k = 9;
#pragma unroll
        for (int i = 0; i < 9; ++i)
#pragma unroll
            for (int j = i; j < 9; ++j) {
                const float coef = (i == j) ? 1.f : 2.f;
                ex2 = fmaf(coef * w[i] * w[j], stc[k], ex2);
                ++k;
            }
        ex2 *= invN;
        const float var   = ex2 - mean * mean;
        const float scale = gamma[o] * rsqrtf(var + BN_EPS);
        const float bias  = fmaf(-mean, scale, beta[o]);

        affs[0][o] = (w[0] + w[4] + w[7]) * scale;
        affs[1][o] = (w[1] + w[5] + w[8]) * scale;
        affs[2][o] = (w[2] + w[6]) * scale;
        affs[3][o] =  w[3] * scale;
        affs[4][o] =  w[4] * scale;
        affs[5][o] =  w[5] * scale;
        affs[6][o] =  w[6] * scale;
        affs[7][o] =  w[7] * scale;
        affs[8][o] =  w[8] * scale;
        affs[9][o] =  bias;
    }
    __syncthreads();

    const float a0   = affs[0][lane];
    const float a1   = affs[1][lane];
    const float a2   = affs[2][lane];
    const float a3   = affs[3][lane];
    const float u4   = affs[4][lane];
    const float u5   = affs[5][lane];
    const float u6   = affs[6][lane];
    const float u7   = affs[7][lane];
    const float u8   = affs[8][lane];
    const float bias = affs[9][lane];

    const int gwave = blockIdx.x * 4 + wib;          // 0..9999

#define DOT(P_, OFS_) \
    fmaf(rdlane(q.x, (P_) + (OFS_)), a0, \
    fmaf(rdlane(q.y, (P_) + (OFS_)), a1, \
    fmaf(rdlane(q.z, (P_) + (OFS_)), a2, \
         rdlane(q.w, (P_) + (OFS_)) * a3)))

#pragma unroll
    for (int it = 0; it < 2; ++it) {
        const int vA = gwave * 4 + it * 2;           // balanced: 2 pairs/wave
        const int vB = vA + 1;

        const int vv = vA + (lane >> 5);
        const float4 q = voxels[(size_t)vv * P_N + (lane & 31)];

        const int nA = __builtin_amdgcn_readfirstlane(npts_arr[vA]);
        const int nB = __builtin_amdgcn_readfirstlane(npts_arr[vB]);

        const float4 mA = means[vA];
        const float4 mB = means[vB];
        const float cyA = cyv[vA];
        const float cyB = cyv[vB];

        const float bA = -fmaf(mA.x, u4, fmaf(mA.y, u5, fmaf(mA.z, u6,
                           fmaf(mA.w, u7, cyA * u8))));
        const float bB = -fmaf(mB.x, u4, fmaf(mB.y, u5, fmaf(mB.z, u6,
                           fmaf(mB.w, u7, cyB * u8))));

        float e0 = -3.4e38f, e1 = -3.4e38f;
        {
            int pp = 0;
            for (; pp + 1 < nA; pp += 2) {
                const float d0 = DOT(pp, 0);
                const float d1 = DOT(pp + 1, 0);
                e0 = fmaxf(e0, d0);
                e1 = fmaxf(e1, d1);
            }
            if (pp < nA) e0 = fmaxf(e0, DOT(pp, 0));
        }
        float mfA = fmaxf(e0, e1) + bA;
        if (nA < P_N) mfA = fmaxf(mfA, 0.f);         // masked rows: x = 0
        out[(size_t)vA * 64 + lane] = fmaxf(mfA + bias, 0.f);

        float g0 = -3.4e38f, g1 = -3.4e38f;
        {
            int pp = 0;
            for (; pp + 1 < nB; pp += 2) {
                const float d0 = DOT(pp, 32);
                const float d1 = DOT(pp + 1, 32);
                g0 = fmaxf(g0, d0);
                g1 = fmaxf(g1, d1);
            }
            if (pp < nB) g0 = fmaxf(g0, DOT(pp, 32));
        }
        float mfB = fmaxf(g0, g1) + bB;
        if (nB < P_N) mfB = fmaxf(mfB, 0.f);
        out[(size_t)vB * 64 + lane] = fmaxf(mfB + bias, 0.f);
    }
#undef DOT
}

// ---------------------------------------------------------------------------
extern "C" void kernel_launch(void* const* d_in, const int* in_sizes, int n_in,
                              void* d_out, int out_size, void* d_ws, size_t ws_size,
                              hipStream_t stream)
{
    const float4* voxels = (const float4*)d_in[0];
    const int*    npts   = (const int*)d_in[1];
    const int*    coors  = (const int*)d_in[2];
    const float*  W      = (const float*)d_in[3];
    const float*  gamma  = (const float*)d_in[4];
    const float*  beta   = (const float*)d_in[5];
    float*        out    = (float*)d_out;
    float*        ws     = (float*)d_ws;

    hipMemsetAsync(d_ws, 0, CNT_BYTES, stream);   // sharded counters
    stats_kernel<<<SBLK, 256, 0, stream>>>(voxels, npts, coors, ws);
    pfn_kernel  <<<PBLK, 256, 0, stream>>>(voxels, npts, W, gamma, beta, ws, out);
}

// Round 14
// 113.022 us; speedup vs baseline: 1.2555x; 1.0236x over previous
//
#include <hip/hip_runtime.h>
#include <hip/hip_bf16.h>

#define V_N   40000
#define P_N   32
#define NTOT  (V_N * P_N)
#define VXc   0.16f
#define VYc   0.16f
#define XOFF  0.08f
#define YOFF  (-39.6f)
#define BN_EPS 1e-5f

#define SBLK  500                    // stats: 2000 waves x 5 iters x 4 voxels
#define PBLK  2500                   // pfn: 10000 waves x exactly 2 pairs
#define NSHARD 16                    // atomic shards per counter (chain depth ~31)
// counter (i, shard s) at float index (i*NSHARD+s)*32 (own 128B line)
#define CNT_BYTES  (54 * NSHARD * 32 * 4)     // 110592
#define MEANS_OFF  131072                     // float4[V_N]
#define CY_OFF     (MEANS_OFF + V_N * 16)     // float[V_N]

#define FOR_S(X) X(0) X(1) X(2) X(3) X(4) X(5) X(6) X(7) X(8)
#define FOR_M(X) \
  X(0,0) X(0,1) X(0,2) X(0,3) X(0,4) X(0,5) X(0,6) X(0,7) X(0,8) \
  X(1,1) X(1,2) X(1,3) X(1,4) X(1,5) X(1,6) X(1,7) X(1,8) \
  X(2,2) X(2,3) X(2,4) X(2,5) X(2,6) X(2,7) X(2,8) \
  X(3,3) X(3,4) X(3,5) X(3,6) X(3,7) X(3,8) \
  X(4,4) X(4,5) X(4,6) X(4,7) X(4,8) \
  X(5,5) X(5,6) X(5,7) X(5,8) \
  X(6,6) X(6,7) X(6,8) \
  X(7,7) X(7,8) \
  X(8,8)

__device__ __forceinline__ float rdlane(float x, int l) {
    return __uint_as_float(__builtin_amdgcn_readlane(__float_as_uint(x), l));
}

// DPP move with zero-fill (VALU pipe -- no DS traffic; proven correct in R8)
template <int CTRL>
__device__ __forceinline__ float dpp0(float x) {
    return __int_as_float(__builtin_amdgcn_update_dpp(
        0, __float_as_int(x), CTRL, 0xF, 0xF, true));
}

// sum of this lane's 32-lane half, uniform within the half
__device__ __forceinline__ float half_sum32(float x, bool hi) {
    x += dpp0<0x111>(x);   // row_shr:1
    x += dpp0<0x112>(x);   // row_shr:2
    x += dpp0<0x114>(x);   // row_shr:4
    x += dpp0<0x118>(x);   // row_shr:8   -> lane15/31/47/63 = row sums
    x += dpp0<0x142>(x);   // row_bcast15 -> lane31 = sum(0..31), lane63 = sum(32..63)
    const float a = rdlane(x, 31);
    const float b = rdlane(x, 63);
    return hi ? b : a;
}

// full 64-lane sum, uniform
__device__ __forceinline__ float full_sum64(float x) {
    x += dpp0<0x111>(x);
    x += dpp0<0x112>(x);
    x += dpp0<0x114>(x);
    x += dpp0<0x118>(x);
    x += dpp0<0x142>(x);
    x += dpp0<0x143>(x);   // row_bcast31 -> lane63 = total
    return rdlane(x, 63);
}

#define DECL_S(i)   float S##i = 0.f;
#define DECL_M(i,j) float M##i##_##j = 0.f;
#define ACC_S(i)    S##i += f##i;
#define ACC_M(i,j)  M##i##_##j = fmaf(f##i, f##j, M##i##_##j);
#define RED_S(i)    S##i = full_sum64(S##i);
#define RED_M(i,j)  M##i##_##j = full_sum64(M##i##_##j);
#define ST_S(i)     r[k++] = S##i;
#define ST_M(i,j)   r[k++] = M##i##_##j;

// per-voxel stat accumulation; per-voxel xyz mean via DPP half-sums
#define STAT_BODY(q, v)                                                       \
        {                                                                     \
            const int   npts = npts_arr[v];                                   \
            const float inv  = 1.f / (float)npts;                             \
            const float mx = half_sum32(q.x, hi) * inv;                       \
            const float my = half_sum32(q.y, hi) * inv;                       \
            const float mz = half_sum32(q.z, hi) * inv;                       \
            const float cx = (float)coors[2 * (v)]     * VXc + XOFF;          \
            const float cy = (float)coors[2 * (v) + 1] * VYc + YOFF;          \
            if (p == 0) { means[v] = make_float4(mx, my, mz, cx);             \
                          cyv[v] = cy; }                                      \
            const float g  = (p < npts) ? 1.f : 0.f;                          \
            const float f0 = q.x * g;                                         \
            const float f1 = q.y * g;                                         \
            const float f2 = q.z * g;                                         \
            const float f3 = q.w * g;                                         \
            const float f4 = (q.x - mx) * g;                                  \
            const float f5 = (q.y - my) * g;                                  \
            const float f6 = (q.z - mz) * g;                                  \
            const float f7 = (q.x - cx) * g;                                  \
            const float f8 = (q.y - cy) * g;                                  \
            FOR_S(ACC_S)                                                      \
            FOR_M(ACC_M)                                                      \
        }

// ---------------------------------------------------------------------------
// Kernel 1: moments -> 16-way sharded padded atomic counters + per-voxel
// (mean_xyz, cx) & cy. 4 voxels/iter via 2 independent 1-KiB loads; all
// cross-lane reduction on the VALU via DPP (no DS-pipe serialization).
// ---------------------------------------------------------------------------
__global__ __launch_bounds__(256) void stats_kernel(
    const float4* __restrict__ voxels,
    const int*    __restrict__ npts_arr,
    const int*    __restrict__ coors,
    float*        __restrict__ ws)
{
    float*  cnt   = ws;
    float4* means = (float4*)((char*)ws + MEANS_OFF);
    float*  cyv   = (float*)((char*)ws + CY_OFF);

    const int  lane = threadIdx.x & 63;
    const int  p    = lane & 31;
    const int  half = lane >> 5;
    const bool hi   = lane >= 32;
    const int  gw   = (blockIdx.x * 256 + threadIdx.x) >> 6;
    const int  nw   = (SBLK * 256) >> 6;     // 2000 waves

    FOR_S(DECL_S)
    FOR_M(DECL_M)

    for (int vb = gw * 4; vb < V_N; vb += nw * 4) {   // exactly 5 iters
        const int vA = vb + half;
        const int vB = vb + 2 + half;
        float4 q1 = voxels[(size_t)vA * P_N + p];     // both loads in flight
        float4 q2 = voxels[(size_t)vB * P_N + p];
        STAT_BODY(q1, vA)
        STAT_BODY(q2, vB)
    }

    FOR_S(RED_S)
    FOR_M(RED_M)

    __shared__ float red[4][54];
    const int wib = threadIdx.x >> 6;
    if (lane == 0) {
        float* r = red[wib];
        int k = 0;
        FOR_S(ST_S)
        FOR_M(ST_M)
    }
    __syncthreads();
    if (threadIdx.x < 54) {
        float s = red[0][threadIdx.x] + red[1][threadIdx.x]
                + red[2][threadIdx.x] + red[3][threadIdx.x];
        atomicAdd(&cnt[(threadIdx.x * NSHARD + (blockIdx.x & (NSHARD - 1))) * 32], s);
    }
}

// ---------------------------------------------------------------------------
// Kernel 2: per-block head computes the BN affine from the sharded counters
// (plain loads -- kernel boundary gives coherence), LDS-broadcasts; balanced
// main loop: 4 waves x exactly 2 pairs, readlane broadcast, dual max chains.
// ---------------------------------------------------------------------------
__global__ __launch_bounds__(256) void pfn_kernel(
    const float4* __restrict__ voxels,
    const int*    __restrict__ npts_arr,
    const float*  __restrict__ W,        // (64, 9) row-major
    const float*  __restrict__ gamma,
    const float*  __restrict__ beta,
    const float*  __restrict__ ws,
    float*        __restrict__ out)      // (V, 64)
{
    const float*  cnt   = ws;
    const float4* means = (const float4*)((const char*)ws + MEANS_OFF);
    const float*  cyv   = (const float*)((const char*)ws + CY_OFF);

    __shared__ float stc[54];
    __shared__ float affs[10][64];

    const int lane = threadIdx.x & 63;
    const int wib  = threadIdx.x >> 6;

    // --- block head: shard-sum + affine (fully parallel across blocks) ---
    if (threadIdx.x < 54) {
        float s = 0.f;
#pragma unroll
        for (int sh = 0; sh < NSHARD; ++sh)
            s += cnt[(threadIdx.x * NSHARD + sh) * 32];
        stc[threadIdx.x] = s;
    }
    __syncthreads();
    if (threadIdx.x < 64) {
        const int o = threadIdx.x;
        float w[9];
#pragma unroll
        for (int c = 0; c < 9; ++c) w[c] = W[o * 9 + c];

        const float invN = 1.f / (float)NTOT;
        float mean = 0.f;
#pragma unroll
        for (int c = 0; c < 9; ++c) mean = fmaf(w[c], stc[c], mean);
        mean *= invN;

        float ex2 = 0.f;
        int k = 9;
#pragma unroll
        for (int i = 0; i < 9; ++i)
#pragma unroll
            for (int j = i; j < 9; ++j) {
                const float coef = (i == j) ? 1.f : 2.f;
                ex2 = fmaf(coef * w[i] * w[j], stc[k], ex2);
                ++k;
            }
        ex2 *= invN;
        const float var   = ex2 - mean * mean;
        const float scale = gamma[o] * rsqrtf(var + BN_EPS);
        const float bias  = fmaf(-mean, scale, beta[o]);

        affs[0][o] = (w[0] + w[4] + w[7]) * scale;
        affs[1][o] = (w[1] + w[5] + w[8]) * scale;
        affs[2][o] = (w[2] + w[6]) * scale;
        affs[3][o] =  w[3] * scale;
        affs[4][o] =  w[4] * scale;
        affs[5][o] =  w[5] * scale;
        affs[6][o] =  w[6] * scale;
        affs[7][o] =  w[7] * scale;
        affs[8][o] =  w[8] * scale;
        affs[9][o] =  bias;
    }
    __syncthreads();

    const float a0   = affs[0][lane];
    const float a1   = affs[1][lane];
    const float a2   = affs[2][lane];
    const float a3   = affs[3][lane];
    const float u4   = affs[4][lane];
    const float u5   = affs[5][lane];
    const float u6   = affs[6][lane];
    const float u7   = affs[7][lane];
    const float u8   = affs[8][lane];
    const float bias = affs[9][lane];

    const int gwave = blockIdx.x * 4 + wib;          // 0..9999

#define DOT(P_, OFS_) \
    fmaf(rdlane(q.x, (P_) + (OFS_)), a0, \
    fmaf(rdlane(q.y, (P_) + (OFS_)), a1, \
    fmaf(rdlane(q.z, (P_) + (OFS_)), a2, \
         rdlane(q.w, (P_) + (OFS_)) * a3)))

#pragma unroll
    for (int it = 0; it < 2; ++it) {
        const int vA = gwave * 4 + it * 2;           // balanced: 2 pairs/wave
        const int vB = vA + 1;

        const int vv = vA + (lane >> 5);
        const float4 q = voxels[(size_t)vv * P_N + (lane & 31)];

        const int nA = __builtin_amdgcn_readfirstlane(npts_arr[vA]);
        const int nB = __builtin_amdgcn_readfirstlane(npts_arr[vB]);

        const float4 mA = means[vA];
        const float4 mB = means[vB];
        const float cyA = cyv[vA];
        const float cyB = cyv[vB];

        const float bA = -fmaf(mA.x, u4, fmaf(mA.y, u5, fmaf(mA.z, u6,
                           fmaf(mA.w, u7, cyA * u8))));
        const float bB = -fmaf(mB.x, u4, fmaf(mB.y, u5, fmaf(mB.z, u6,
                           fmaf(mB.w, u7, cyB * u8))));

        float e0 = -3.4e38f, e1 = -3.4e38f;
        {
            int pp = 0;
            for (; pp + 1 < nA; pp += 2) {
                const float d0 = DOT(pp, 0);
                const float d1 = DOT(pp + 1, 0);
                e0 = fmaxf(e0, d0);
                e1 = fmaxf(e1, d1);
            }
            if (pp < nA) e0 = fmaxf(e0, DOT(pp, 0));
        }
        float mfA = fmaxf(e0, e1) + bA;
        if (nA < P_N) mfA = fmaxf(mfA, 0.f);         // masked rows: x = 0
        out[(size_t)vA * 64 + lane] = fmaxf(mfA + bias, 0.f);

        float g0 = -3.4e38f, g1 = -3.4e38f;
        {
            int pp = 0;
            for (; pp + 1 < nB; pp += 2) {
                const float d0 = DOT(pp, 32);
                const float d1 = DOT(pp + 1, 32);
                g0 = fmaxf(g0, d0);
                g1 = fmaxf(g1, d1);
            }
            if (pp < nB) g0 = fmaxf(g0, DOT(pp, 32));
        }
        float mfB = fmaxf(g0, g1) + bB;
        if (nB < P_N) mfB = fmaxf(mfB, 0.f);
        out[(size_t)vB * 64 + lane] = fmaxf(mfB + bias, 0.f);
    }
#undef DOT
}

// ---------------------------------------------------------------------------
extern "C" void kernel_launch(void* const* d_in, const int* in_sizes, int n_in,
                              void* d_out, int out_size, void* d_ws, size_t ws_size,
                              hipStream_t stream)
{
    const float4* voxels = (const float4*)d_in[0];
    const int*    npts   = (const int*)d_in[1];
    const int*    coors  = (const int*)d_in[2];
    const float*  W      = (const float*)d_in[3];
    const float*  gamma  = (const float*)d_in[4];
    const float*  beta   = (const float*)d_in[5];
    float*        out    = (float*)d_out;
    float*        ws     = (float*)d_ws;

    hipMemsetAsync(d_ws, 0, CNT_BYTES, stream);   // sharded counters
    stats_kernel<<<SBLK, 256, 0, stream>>>(voxels, npts, coors, ws);
    pfn_kernel  <<<PBLK, 256, 0, stream>>>(voxels, npts, W, gamma, beta, ws, out);
}